// Round 4
// baseline (65.235 us; speedup 1.0000x reference)
//
#include <hip/hip_runtime.h>
#include <math.h>

#define NNODE 512
#define NBATCH 4
#define NFEAT 12
#define QKD 128
#define NVD 128
#define EVD 32
#define CATD 160          // NVD + EVD
#define TRD 256
#define NCLS 5
#define NROWS 2048        // NBATCH * NNODE
#define EPSV 1e-5f
#define NSTATBUF 8        // split BN-stat atomic contention 8 ways
#define NCHUNK 4          // j-chunks per row (flash split)
#define JC 128            // j-chunk width
#define TIA 8             // rows per flashA block

// ---------------------------------------------------------------------------
// Kernel 1: Q, K, NV projections. 256 thr, 2 rows/block, grid 1024.
// Blocks 0..15 zero the 8x512-float BN-stats region.
// ---------------------------------------------------------------------------
__global__ __launch_bounds__(256) void qkv_kernel(
    const float* __restrict__ nodes,
    const float* __restrict__ Wq, const float* __restrict__ bq,
    const float* __restrict__ Wk, const float* __restrict__ bk,
    const float* __restrict__ Wnv, const float* __restrict__ bnv,
    float* __restrict__ Q, float* __restrict__ K, float* __restrict__ NV,
    float* __restrict__ stats) {
  const int tid = threadIdx.x;
  const int h = tid >> 7, d = tid & 127;
  const int row = blockIdx.x * 2 + h;
  if (blockIdx.x < 2 * NSTATBUF)       // 16 blocks x 256 = 4096 floats
    stats[blockIdx.x * 256 + tid] = 0.f;
  __shared__ float sn[2][NFEAT];
  if (tid < 2 * NFEAT) sn[tid / NFEAT][tid % NFEAT] = nodes[blockIdx.x * 2 * NFEAT + tid];
  __syncthreads();
  float aq = bq[d], ak = bk[d], av = bnv[d];
#pragma unroll
  for (int k = 0; k < NFEAT; ++k) {
    const float n = sn[h][k];
    aq = fmaf(n, Wq[d * NFEAT + k], aq);
    ak = fmaf(n, Wk[d * NFEAT + k], ak);
    av = fmaf(n, Wnv[d * NFEAT + k], av);
  }
  Q[row * QKD + d]  = aq;
  K[row * QKD + d]  = ak;
  NV[row * NVD + d] = av;
}

// ---------------------------------------------------------------------------
// Kernel 2: flashA. Block = (batch b, j-chunk c, row-group of 8 rows).
// Grid 4*4*64 = 1024, 256 thr (4 waves).
//   phase1: scores for 8 rows x 128 j  (thread = (jj, h); h owns 4 rows)
//   phase2: chunk-local softmax partials: m_loc, l_loc, se_loc; w=exp(s-m)
//   phase3: pnv[i][d] = sum_j w[i][j]*NV[j][d]  (unnormalized)
// ---------------------------------------------------------------------------
__global__ __launch_bounds__(256) void flashA_kernel(
    const float* __restrict__ Q, const float* __restrict__ K,
    const float* __restrict__ NV,
    const float* __restrict__ edges, const float* __restrict__ dist,
    const int* __restrict__ mask,
    float* __restrict__ pnv, float* __restrict__ pm,
    float* __restrict__ pl, float* __restrict__ pse) {
  __shared__ __align__(16) float sQ[TIA][QKD];      // 4 KB
  __shared__ __align__(16) float sS[TIA][JC];       // 4 KB (scores -> w)
  __shared__ __align__(16) float sP[2][TIA][NVD];   // 8 KB (nv partials)

  const int tid = threadIdx.x;
  const int bid = blockIdx.x;           // 0..1023
  const int b   = bid >> 8;             // batch
  const int c   = (bid >> 6) & 3;       // j-chunk
  const int rg  = bid & 63;             // row group
  const int rowbase = b * NNODE + rg * TIA;
  const int jbase = c * JC;

  // stage Q: 8 rows x 128 = 1024 floats (contiguous)
#pragma unroll
  for (int k = 0; k < 4; ++k)
    ((float*)sQ)[tid + k * 256] = Q[(size_t)rowbase * QKD + tid + k * 256];
  __syncthreads();

  // ---- phase 1: scores -------------------------------------------------
  {
    const int jj = tid & 127;           // 0..127
    const int h  = tid >> 7;            // 0..1 -> rows h*4..h*4+3
    float dd[4]; int mm[4];
#pragma unroll
    for (int q = 0; q < 4; ++q) {
      const size_t off = (size_t)(rowbase + h * 4 + q) * NNODE + jbase + jj;
      dd[q] = dist[off];
      mm[q] = mask[off];
    }
    const float4* K4 = (const float4*)(K + (size_t)(b * NNODE + jbase + jj) * QKD);
    float acc[4] = {0.f, 0.f, 0.f, 0.f};
#pragma unroll 8
    for (int kk = 0; kk < QKD / 4; ++kk) {
      const float4 kv = K4[kk];
#pragma unroll
      for (int q = 0; q < 4; ++q) {
        const float4 qv = ((const float4*)sQ[h * 4 + q])[kk];
        acc[q] += qv.x * kv.x + qv.y * kv.y + qv.z * kv.z + qv.w * kv.w;
      }
    }
    const float coeff = 0.0883883476483184f;  // 1/sqrt(128)
#pragma unroll
    for (int q = 0; q < 4; ++q) {
      float s = acc[q] * coeff / (dd[q] + 1.0f);
      if (mm[q]) s = -__builtin_inff();
      sS[h * 4 + q][jj] = s;
    }
  }
  __syncthreads();

  // ---- phase 2: chunk-local softmax partials (wave wv -> rows 2wv,2wv+1)
  {
    const int wv   = tid >> 6;
    const int lane = tid & 63;
#pragma unroll
    for (int rr = 0; rr < 2; ++rr) {
      const int r = 2 * wv + rr;
      const float v0 = sS[r][lane];
      const float v1 = sS[r][lane + 64];
      float m = fmaxf(v0, v1);
#pragma unroll
      for (int s = 1; s < 64; s <<= 1) m = fmaxf(m, __shfl_xor(m, s, 64));
      float w0, w1;
      if (m > -__builtin_inff()) {      // wave-uniform
        w0 = __expf(v0 - m);
        w1 = __expf(v1 - m);
      } else {                          // fully-masked chunk
        w0 = 0.f; w1 = 0.f;
      }
      sS[r][lane]      = w0;
      sS[r][lane + 64] = w1;
      const float* erow = edges + (size_t)(rowbase + r) * NNODE + jbase;
      float l  = w0 + w1;
      float se = w0 * erow[lane] + w1 * erow[lane + 64];
#pragma unroll
      for (int s = 1; s < 64; s <<= 1) {
        l  += __shfl_xor(l, s, 64);
        se += __shfl_xor(se, s, 64);
      }
      if (lane == 0) {
        const int o = c * NROWS + rowbase + r;
        pm[o] = m; pl[o] = l; pse[o] = se;
      }
    }
  }
  __syncthreads();

  // ---- phase 3: pnv = w @ NV (2 j-groups of 64), LDS combine -----------
  {
    const int d = tid & 127;
    const int g = tid >> 7;             // 0..1 -> j in [g*64, g*64+64)
    float acc[TIA] = {0.f, 0.f, 0.f, 0.f, 0.f, 0.f, 0.f, 0.f};
    const float* __restrict__ NVb =
        NV + (size_t)(b * NNODE + jbase + g * 64) * NVD + d;
#pragma unroll 8
    for (int jj = 0; jj < 64; ++jj) {
      const float nv = NVb[(size_t)jj * NVD];
#pragma unroll
      for (int i = 0; i < TIA; ++i)
        acc[i] = fmaf(sS[i][g * 64 + jj], nv, acc[i]);
    }
#pragma unroll
    for (int i = 0; i < TIA; ++i) sP[g][i][d] = acc[i];
  }
  __syncthreads();
#pragma unroll
  for (int k = 0; k < 4; ++k) {
    const int idx = tid + k * 256;
    const int i = idx >> 7, d = idx & 127;
    pnv[((size_t)c * NROWS + rowbase + i) * NVD + d] = sP[0][i][d] + sP[1][i][d];
  }
}

// ---------------------------------------------------------------------------
// Kernel 3: passB + transform fused. 512 blocks x 256 thr, 4 rows/block.
//   combine 4 chunks (flash rescale) -> cat = tanh(node|edge) in LDS
//   vals = cat @ Wt^T + bt  (thread = output col o, streams own Wt row)
//   + BN stat atomics
// ---------------------------------------------------------------------------
__global__ __launch_bounds__(256) void passBtrans_kernel(
    const float* __restrict__ pnv, const float* __restrict__ pm,
    const float* __restrict__ pl, const float* __restrict__ pse,
    const float* __restrict__ Wev, const float* __restrict__ bev,
    const float* __restrict__ Wt, const float* __restrict__ bt,
    float* __restrict__ vals, float* __restrict__ stats) {
  __shared__ __align__(16) float sC[4][CATD];     // 2.5 KB
  const int tid = threadIdx.x;
  const int bid = blockIdx.x;          // 0..511
  const int row0 = bid * 4;

  // node part: idx = (r,d) over 4x128, 2 per thread
#pragma unroll
  for (int k = 0; k < 2; ++k) {
    const int idx = tid + k * 256;
    const int r = idx >> 7, d = idx & 127;
    const int row = row0 + r;
    float mg = -__builtin_inff();
#pragma unroll
    for (int c = 0; c < NCHUNK; ++c) mg = fmaxf(mg, pm[c * NROWS + row]);
    float lg = 0.f, nv = 0.f;
#pragma unroll
    for (int c = 0; c < NCHUNK; ++c) {
      const float mc = pm[c * NROWS + row];
      if (mc > -__builtin_inff()) {
        const float sc = __expf(mc - mg);
        lg = fmaf(pl[c * NROWS + row], sc, lg);
        nv = fmaf(pnv[((size_t)c * NROWS + row) * NVD + d], sc, nv);
      }
    }
    const float inv = (lg > 0.f) ? 1.f / lg : 0.f;
    sC[r][d] = tanhf(nv * inv);
  }
  // edge part: 4 rows x 32 dims = 128 threads
  if (tid < 4 * EVD) {
    const int r = tid >> 5, de = tid & 31;
    const int row = row0 + r;
    float mg = -__builtin_inff();
#pragma unroll
    for (int c = 0; c < NCHUNK; ++c) mg = fmaxf(mg, pm[c * NROWS + row]);
    float lg = 0.f, seg = 0.f;
#pragma unroll
    for (int c = 0; c < NCHUNK; ++c) {
      const float mc = pm[c * NROWS + row];
      if (mc > -__builtin_inff()) {
        const float sc = __expf(mc - mg);
        lg  = fmaf(pl[c * NROWS + row], sc, lg);
        seg = fmaf(pse[c * NROWS + row], sc, seg);
      }
    }
    const float sw = (lg > 0.f) ? 1.f : 0.f;
    const float se = (lg > 0.f) ? seg / lg : 0.f;
    sC[r][NVD + de] = tanhf(fmaf(Wev[de], se, bev[de] * sw));
  }
  __syncthreads();

  // transform: vals[row][o] = sC[row] . Wt[o] + bt[o]
  const int o = tid;
  const float4* __restrict__ w4 = (const float4*)(Wt + (size_t)o * CATD);
  float acc[4] = {0.f, 0.f, 0.f, 0.f};
#pragma unroll 8
  for (int k4 = 0; k4 < CATD / 4; ++k4) {
    const float4 w = w4[k4];
#pragma unroll
    for (int r = 0; r < 4; ++r) {
      const float4 cc = ((const float4*)sC[r])[k4];
      acc[r] += cc.x * w.x + cc.y * w.y + cc.z * w.z + cc.w * w.w;
    }
  }
  const float bto = bt[o];
  float s1 = 0.f, s2 = 0.f;
#pragma unroll
  for (int r = 0; r < 4; ++r) {
    const float v2 = acc[r] + bto;
    vals[(size_t)(row0 + r) * TRD + o] = v2;
    s1 += v2;
    s2 = fmaf(v2, v2, s2);
  }
  float* sb = stats + (size_t)(bid & (NSTATBUF - 1)) * 2 * TRD;
  atomicAdd(&sb[o], s1);
  atomicAdd(&sb[TRD + o], s2);
}

// ---------------------------------------------------------------------------
// Kernel 4: fused BN-fold + classifier. 512 blocks x 256 thr, 4 rows/block.
// ---------------------------------------------------------------------------
__global__ __launch_bounds__(256) void outbn_kernel(
    const float* __restrict__ vals, const float* __restrict__ stats,
    const float* __restrict__ gamma, const float* __restrict__ beta,
    const float* __restrict__ Wc, const float* __restrict__ bc,
    float* __restrict__ out) {
  __shared__ float sW[NCLS][TRD];
  __shared__ float sb[NCLS];
  __shared__ float red[4][NCLS];
  const int tid = threadIdx.x;
  const int o = tid;                   // 0..255
  float s1 = 0.f, s2 = 0.f;
#pragma unroll
  for (int k = 0; k < NSTATBUF; ++k) {
    s1 += stats[k * 2 * TRD + o];
    s2 += stats[k * 2 * TRD + TRD + o];
  }
  const float invN = 1.0f / (float)NROWS;
  const float mu  = s1 * invN;
  const float var = s2 * invN - mu * mu;
  const float inv = 1.0f / sqrtf(var + EPSV);
  const float g = gamma[o] * inv;
  const float bterm = beta[o] - mu * g;
  float v[NCLS];
#pragma unroll
  for (int c = 0; c < NCLS; ++c) {
    const float wc = Wc[c * TRD + o];
    sW[c][o] = wc * g;
    v[c] = wc * bterm;
  }
#pragma unroll
  for (int s = 1; s < 64; s <<= 1) {
#pragma unroll
    for (int c = 0; c < NCLS; ++c) v[c] += __shfl_xor(v[c], s, 64);
  }
  if ((tid & 63) == 0) {
#pragma unroll
    for (int c = 0; c < NCLS; ++c) red[tid >> 6][c] = v[c];
  }
  __syncthreads();
  if (tid < NCLS)
    sb[tid] = bc[tid] + red[0][tid] + red[1][tid] + red[2][tid] + red[3][tid];
  __syncthreads();

  const int lane = tid & 63;
  const int row = blockIdx.x * 4 + (tid >> 6);
  float vv[TRD / 64];
#pragma unroll
  for (int t = 0; t < TRD / 64; ++t)
    vv[t] = vals[(size_t)row * TRD + lane + 64 * t];
#pragma unroll
  for (int c = 0; c < NCLS; ++c) {
    float p = 0.f;
#pragma unroll
    for (int t = 0; t < TRD / 64; ++t)
      p = fmaf(vv[t], sW[c][lane + 64 * t], p);
#pragma unroll
    for (int s = 1; s < 64; s <<= 1) p += __shfl_xor(p, s, 64);
    if (lane == 0) out[(size_t)row * NCLS + c] = p + sb[c];
  }
}

// ---------------------------------------------------------------------------
extern "C" void kernel_launch(void* const* d_in, const int* in_sizes, int n_in,
                              void* d_out, int out_size, void* d_ws, size_t ws_size,
                              hipStream_t stream) {
  (void)in_sizes; (void)n_in; (void)out_size; (void)ws_size;
  const float* nodes = (const float*)d_in[0];
  const float* edges = (const float*)d_in[1];
  const float* dist  = (const float*)d_in[2];
  const int*   mask  = (const int*)d_in[3];
  const float* Wq  = (const float*)d_in[4];
  const float* bq  = (const float*)d_in[5];
  const float* Wk  = (const float*)d_in[6];
  const float* bk  = (const float*)d_in[7];
  const float* Wnv = (const float*)d_in[8];
  const float* bnv = (const float*)d_in[9];
  const float* Wev = (const float*)d_in[10];
  const float* bev = (const float*)d_in[11];
  const float* Wt  = (const float*)d_in[12];
  const float* bt  = (const float*)d_in[13];
  const float* gamma = (const float*)d_in[14];
  const float* beta  = (const float*)d_in[15];
  const float* Wc  = (const float*)d_in[16];
  const float* bc  = (const float*)d_in[17];

  float* ws    = (float*)d_ws;
  float* Q     = ws;                               // 2048*128
  float* K     = Q   + (size_t)NROWS * QKD;        // 2048*128
  float* NV    = K   + (size_t)NROWS * QKD;        // 2048*128
  float* pnv   = NV  + (size_t)NROWS * NVD;        // 4*2048*128
  float* pm    = pnv + (size_t)NCHUNK * NROWS * NVD;  // 4*2048
  float* pl    = pm  + (size_t)NCHUNK * NROWS;     // 4*2048
  float* pse   = pl  + (size_t)NCHUNK * NROWS;     // 4*2048
  float* vals  = pse + (size_t)NCHUNK * NROWS;     // 2048*256
  float* stats = vals + (size_t)NROWS * TRD;       // 8*512 (sum|sqsum)
  float* outp  = (float*)d_out;

  qkv_kernel<<<NROWS / 2, 256, 0, stream>>>(nodes, Wq, bq, Wk, bk, Wnv, bnv,
                                            Q, K, NV, stats);
  flashA_kernel<<<NBATCH * NCHUNK * (NNODE / TIA), 256, 0, stream>>>(
      Q, K, NV, edges, dist, mask, pnv, pm, pl, pse);
  passBtrans_kernel<<<NROWS / 4, 256, 0, stream>>>(pnv, pm, pl, pse, Wev, bev,
                                                   Wt, bt, vals, stats);
  outbn_kernel<<<NROWS / 4, 256, 0, stream>>>(vals, stats, gamma, beta,
                                              Wc, bc, outp);
}

// Round 5
// 42.929 us; speedup vs baseline: 1.5196x; 1.5196x over previous
//
#include <hip/hip_runtime.h>
#include <math.h>

#define NNODE 512
#define NBATCH 4
#define NFEAT 12
#define QKD 128
#define NVD 128
#define EVD 32
#define CATD 160          // NVD + EVD
#define TRD 256
#define NCLS 5
#define NROWS 2048        // NBATCH * NNODE
#define EPSV 1e-5f
#define NSTATBUF 8        // split BN-stat atomic contention 8 ways
#define NCHUNK 4          // j-chunks per row (flash split)
#define JC 128            // j-chunk width
#define RB 16             // rows per flashA block (MFMA M=16)
#define SSP 132           // sS padded stride (f32): +4 -> 2-way banks on frag reads

typedef float floatx4 __attribute__((ext_vector_type(4)));
typedef __bf16 bf16x8 __attribute__((ext_vector_type(8)));
typedef unsigned short ushort_t;
typedef ushort_t ushort8 __attribute__((ext_vector_type(8)));
typedef ushort_t ushort4v __attribute__((ext_vector_type(4)));

// f32 -> bf16 bits, round-to-nearest-even
static __device__ __forceinline__ ushort_t f2bf(float x) {
  unsigned int u = __float_as_uint(x);
  return (ushort_t)((u + 0x7fffu + ((u >> 16) & 1u)) >> 16);
}

// ---------------------------------------------------------------------------
// Kernel 1: Q, K, NV projections (f32). 256 thr, 2 rows/block, grid 1024.
// Blocks 0..15 zero the BN-stats region.
// ---------------------------------------------------------------------------
__global__ __launch_bounds__(256) void qkv_kernel(
    const float* __restrict__ nodes,
    const float* __restrict__ Wq, const float* __restrict__ bq,
    const float* __restrict__ Wk, const float* __restrict__ bk,
    const float* __restrict__ Wnv, const float* __restrict__ bnv,
    float* __restrict__ Q, float* __restrict__ K, float* __restrict__ NV,
    float* __restrict__ stats) {
  const int tid = threadIdx.x;
  const int h = tid >> 7, d = tid & 127;
  const int row = blockIdx.x * 2 + h;
  if (blockIdx.x < 2 * NSTATBUF)       // 16 blocks x 256 = 4096 floats
    stats[blockIdx.x * 256 + tid] = 0.f;
  __shared__ float sn[2][NFEAT];
  if (tid < 2 * NFEAT) sn[tid / NFEAT][tid % NFEAT] = nodes[blockIdx.x * 2 * NFEAT + tid];
  __syncthreads();
  float aq = bq[d], ak = bk[d], av = bnv[d];
#pragma unroll
  for (int k = 0; k < NFEAT; ++k) {
    const float n = sn[h][k];
    aq = fmaf(n, Wq[d * NFEAT + k], aq);
    ak = fmaf(n, Wk[d * NFEAT + k], ak);
    av = fmaf(n, Wnv[d * NFEAT + k], av);
  }
  Q[row * QKD + d]  = aq;
  K[row * QKD + d]  = ak;
  NV[row * NVD + d] = av;
}

// ---------------------------------------------------------------------------
// Kernel 2: flashA via MFMA (bf16). Block = (batch b, chunk c, 16 rows).
// Grid 4*4*32 = 512, 256 thr (4 waves). Fragment layout (16x16x32 bf16):
//   A: lane l -> row=l&15, k = 4*(l>>4) + {0..3}, elems 4..7 at k+16
//   B: lane l -> col=l&15, same k pattern              [m156/m162 tr-read]
//   C: lane l, reg r -> col=l&15, row=(l>>4)*4+r       [m89 verified]
// ---------------------------------------------------------------------------
__global__ __launch_bounds__(256) void flashA_kernel(
    const float* __restrict__ Q, const float* __restrict__ K,
    const float* __restrict__ NV,
    const float* __restrict__ edges, const float* __restrict__ dist,
    const int* __restrict__ mask,
    float* __restrict__ pnv, float* __restrict__ pm,
    float* __restrict__ pl, float* __restrict__ pse) {
  __shared__ ushort_t sKB[JC][136];     // K chunk bf16, padded: 34.8 KB
  __shared__ float sS[RB][SSP];         // scores -> w (f32): 8.4 KB
  __shared__ float sM[RB], sL[RB], sSE[RB];

  const int tid  = threadIdx.x;
  const int bid  = blockIdx.x;          // 0..511
  const int b    = bid >> 7;            // batch
  const int c    = (bid >> 5) & 3;      // j-chunk
  const int rg   = bid & 31;            // row group
  const int rowbase = b * NNODE + rg * RB;
  const int jbase   = c * JC;

  const int lane = tid & 63;
  const int wv   = tid >> 6;            // wave 0..3
  const int col  = lane & 15;           // frag row/col selector
  const int kg   = lane >> 4;           // k-group 0..3

  // ---- stage K chunk -> bf16 LDS (coalesced reads, b64 writes) ---------
  {
    const float* __restrict__ Kb = K + (size_t)(b * NNODE + jbase) * QKD;
    const int jr = tid >> 5;            // 0..7 row within pass
    const int d0 = (tid & 31) * 4;
#pragma unroll 4
    for (int p = 0; p < 16; ++p) {
      const int j = p * 8 + jr;
      const float4 kv = *(const float4*)(Kb + (size_t)j * QKD + d0);
      ushort4v w4 = {f2bf(kv.x), f2bf(kv.y), f2bf(kv.z), f2bf(kv.w)};
      *(ushort4v*)&sKB[j][d0] = w4;
    }
  }

  // ---- Q A-fragments direct from global --------------------------------
  bf16x8 aq[4];
  {
    const float* __restrict__ Qr = Q + (size_t)(rowbase + col) * QKD;
#pragma unroll
    for (int ks = 0; ks < 4; ++ks) {
      const float4 lo = *(const float4*)(Qr + ks * 32 + kg * 4);
      const float4 hi = *(const float4*)(Qr + ks * 32 + 16 + kg * 4);
      ushort8 u;
      u[0] = f2bf(lo.x); u[1] = f2bf(lo.y); u[2] = f2bf(lo.z); u[3] = f2bf(lo.w);
      u[4] = f2bf(hi.x); u[5] = f2bf(hi.y); u[6] = f2bf(hi.z); u[7] = f2bf(hi.w);
      aq[ks] = __builtin_bit_cast(bf16x8, u);
    }
  }
  __syncthreads();

  // ---- QK^T MFMAs: wave owns j-tiles {2wv, 2wv+1} ----------------------
  floatx4 acc0 = {0.f, 0.f, 0.f, 0.f};
  floatx4 acc1 = {0.f, 0.f, 0.f, 0.f};
  {
    const int j0 = (wv * 2) * 16 + col;
    const int j1 = (wv * 2 + 1) * 16 + col;
#pragma unroll
    for (int ks = 0; ks < 4; ++ks) {
      const ushort_t* p0 = &sKB[j0][ks * 32 + kg * 4];
      const ushort_t* p1 = &sKB[j1][ks * 32 + kg * 4];
      ushort4v a0 = *(const ushort4v*)p0, b0 = *(const ushort4v*)(p0 + 16);
      ushort4v a1 = *(const ushort4v*)p1, b1 = *(const ushort4v*)(p1 + 16);
      ushort8 u0, u1;
      u0[0]=a0.x; u0[1]=a0.y; u0[2]=a0.z; u0[3]=a0.w;
      u0[4]=b0.x; u0[5]=b0.y; u0[6]=b0.z; u0[7]=b0.w;
      u1[0]=a1.x; u1[1]=a1.y; u1[2]=a1.z; u1[3]=a1.w;
      u1[4]=b1.x; u1[5]=b1.y; u1[6]=b1.z; u1[7]=b1.w;
      acc0 = __builtin_amdgcn_mfma_f32_16x16x32_bf16(
          aq[ks], __builtin_bit_cast(bf16x8, u0), acc0, 0, 0, 0);
      acc1 = __builtin_amdgcn_mfma_f32_16x16x32_bf16(
          aq[ks], __builtin_bit_cast(bf16x8, u1), acc1, 0, 0, 0);
    }
  }

  // ---- scale by coeff/(dist+1), mask -> -inf, store to sS --------------
  {
    const float coeff = 0.0883883476483184f;  // 1/sqrt(128)
#pragma unroll
    for (int t = 0; t < 2; ++t) {
      const int jl = (wv * 2 + t) * 16 + col;
#pragma unroll
      for (int r = 0; r < 4; ++r) {
        const int row = kg * 4 + r;
        const size_t off = (size_t)(rowbase + row) * NNODE + jbase + jl;
        const float a = (t == 0) ? acc0[r] : acc1[r];
        float s = a * coeff / (dist[off] + 1.0f);
        if (mask[off] != 0) s = -__builtin_inff();
        sS[row][jl] = s;
      }
    }
  }
  __syncthreads();

  // ---- softmax partials (wave wv -> rows 4wv..4wv+3) -------------------
  {
    float e0[4], e1[4];
#pragma unroll
    for (int rr = 0; rr < 4; ++rr) {
      const size_t base = (size_t)(rowbase + 4 * wv + rr) * NNODE + jbase;
      e0[rr] = edges[base + lane];
      e1[rr] = edges[base + 64 + lane];
    }
#pragma unroll
    for (int rr = 0; rr < 4; ++rr) {
      const int r = 4 * wv + rr;
      const float v0 = sS[r][lane];
      const float v1 = sS[r][lane + 64];
      float m = fmaxf(v0, v1);
#pragma unroll
      for (int s = 1; s < 64; s <<= 1) m = fmaxf(m, __shfl_xor(m, s, 64));
      float w0 = 0.f, w1 = 0.f;
      if (m > -__builtin_inff()) {      // wave-uniform
        w0 = __expf(v0 - m);
        w1 = __expf(v1 - m);
      }
      sS[r][lane]      = w0;
      sS[r][lane + 64] = w1;
      float l  = w0 + w1;
      float se = fmaf(w0, e0[rr], w1 * e1[rr]);
#pragma unroll
      for (int s = 1; s < 64; s <<= 1) {
        l  += __shfl_xor(l, s, 64);
        se += __shfl_xor(se, s, 64);
      }
      if (lane == 0) { sM[r] = m; sL[r] = l; sSE[r] = se; }
    }
  }
  __syncthreads();

  // ---- PV MFMAs: pnv(16 x 128) = w(16 x 128j) @ NV(128j x 128d) --------
  floatx4 pv0 = {0.f, 0.f, 0.f, 0.f};
  floatx4 pv1 = {0.f, 0.f, 0.f, 0.f};
  {
    bf16x8 aw[4];
#pragma unroll
    for (int ks = 0; ks < 4; ++ks) {
      const float* pw = &sS[col][ks * 32 + kg * 4];
      const float4 lo = *(const float4*)pw;
      const float4 hi = *(const float4*)(pw + 16);
      ushort8 u;
      u[0] = f2bf(lo.x); u[1] = f2bf(lo.y); u[2] = f2bf(lo.z); u[3] = f2bf(lo.w);
      u[4] = f2bf(hi.x); u[5] = f2bf(hi.y); u[6] = f2bf(hi.z); u[7] = f2bf(hi.w);
      aw[ks] = __builtin_bit_cast(bf16x8, u);
    }
    const float* __restrict__ NVb = NV + (size_t)(b * NNODE + jbase) * NVD;
    const int d0 = (wv * 2) * 16 + col;
    const int d1 = (wv * 2 + 1) * 16 + col;
#pragma unroll
    for (int ks = 0; ks < 4; ++ks) {
      ushort8 u0, u1;
#pragma unroll
      for (int i = 0; i < 4; ++i) {
        const size_t jlo = (size_t)(ks * 32 + kg * 4 + i) * NVD;
        const size_t jhi = (size_t)(ks * 32 + 16 + kg * 4 + i) * NVD;
        u0[i]     = f2bf(NVb[jlo + d0]);
        u0[4 + i] = f2bf(NVb[jhi + d0]);
        u1[i]     = f2bf(NVb[jlo + d1]);
        u1[4 + i] = f2bf(NVb[jhi + d1]);
      }
      pv0 = __builtin_amdgcn_mfma_f32_16x16x32_bf16(
          aw[ks], __builtin_bit_cast(bf16x8, u0), pv0, 0, 0, 0);
      pv1 = __builtin_amdgcn_mfma_f32_16x16x32_bf16(
          aw[ks], __builtin_bit_cast(bf16x8, u1), pv1, 0, 0, 0);
    }
  }

  // ---- write partials --------------------------------------------------
#pragma unroll
  for (int t = 0; t < 2; ++t) {
    const int dcol = (wv * 2 + t) * 16 + col;
#pragma unroll
    for (int r = 0; r < 4; ++r) {
      const int row = kg * 4 + r;
      pnv[((size_t)c * NROWS + rowbase + row) * NVD + dcol] =
          (t == 0) ? pv0[r] : pv1[r];
    }
  }
  if (tid < RB) {
    const int o = c * NROWS + rowbase + tid;
    pm[o] = sM[tid]; pl[o] = sL[tid]; pse[o] = sSE[tid];
  }
}

// ---------------------------------------------------------------------------
// Kernel 3: passB + transform fused. 512 blocks x 256 thr, 4 rows/block.
// ---------------------------------------------------------------------------
__global__ __launch_bounds__(256) void passBtrans_kernel(
    const float* __restrict__ pnv, const float* __restrict__ pm,
    const float* __restrict__ pl, const float* __restrict__ pse,
    const float* __restrict__ Wev, const float* __restrict__ bev,
    const float* __restrict__ Wt, const float* __restrict__ bt,
    float* __restrict__ vals, float* __restrict__ stats) {
  __shared__ __align__(16) float sC[4][CATD];     // 2.5 KB
  const int tid = threadIdx.x;
  const int bid = blockIdx.x;          // 0..511
  const int row0 = bid * 4;

#pragma unroll
  for (int k = 0; k < 2; ++k) {
    const int idx = tid + k * 256;
    const int r = idx >> 7, d = idx & 127;
    const int row = row0 + r;
    float mg = -__builtin_inff();
#pragma unroll
    for (int c = 0; c < NCHUNK; ++c) mg = fmaxf(mg, pm[c * NROWS + row]);
    float lg = 0.f, nv = 0.f;
#pragma unroll
    for (int c = 0; c < NCHUNK; ++c) {
      const float mc = pm[c * NROWS + row];
      if (mc > -__builtin_inff()) {
        const float sc = __expf(mc - mg);
        lg = fmaf(pl[c * NROWS + row], sc, lg);
        nv = fmaf(pnv[((size_t)c * NROWS + row) * NVD + d], sc, nv);
      }
    }
    const float inv = (lg > 0.f) ? 1.f / lg : 0.f;
    sC[r][d] = tanhf(nv * inv);
  }
  if (tid < 4 * EVD) {
    const int r = tid >> 5, de = tid & 31;
    const int row = row0 + r;
    float mg = -__builtin_inff();
#pragma unroll
    for (int c = 0; c < NCHUNK; ++c) mg = fmaxf(mg, pm[c * NROWS + row]);
    float lg = 0.f, seg = 0.f;
#pragma unroll
    for (int c = 0; c < NCHUNK; ++c) {
      const float mc = pm[c * NROWS + row];
      if (mc > -__builtin_inff()) {
        const float sc = __expf(mc - mg);
        lg  = fmaf(pl[c * NROWS + row], sc, lg);
        seg = fmaf(pse[c * NROWS + row], sc, seg);
      }
    }
    const float sw = (lg > 0.f) ? 1.f : 0.f;
    const float se = (lg > 0.f) ? seg / lg : 0.f;
    sC[r][NVD + de] = tanhf(fmaf(Wev[de], se, bev[de] * sw));
  }
  __syncthreads();

  const int o = tid;
  const float4* __restrict__ w4 = (const float4*)(Wt + (size_t)o * CATD);
  float acc[4] = {0.f, 0.f, 0.f, 0.f};
#pragma unroll 8
  for (int k4 = 0; k4 < CATD / 4; ++k4) {
    const float4 w = w4[k4];
#pragma unroll
    for (int r = 0; r < 4; ++r) {
      const float4 cc = ((const float4*)sC[r])[k4];
      acc[r] += cc.x * w.x + cc.y * w.y + cc.z * w.z + cc.w * w.w;
    }
  }
  const float bto = bt[o];
  float s1 = 0.f, s2 = 0.f;
#pragma unroll
  for (int r = 0; r < 4; ++r) {
    const float v2 = acc[r] + bto;
    vals[(size_t)(row0 + r) * TRD + o] = v2;
    s1 += v2;
    s2 = fmaf(v2, v2, s2);
  }
  float* sb = stats + (size_t)(bid & (NSTATBUF - 1)) * 2 * TRD;
  atomicAdd(&sb[o], s1);
  atomicAdd(&sb[TRD + o], s2);
}

// ---------------------------------------------------------------------------
// Kernel 4: fused BN-fold + classifier. 512 blocks x 256 thr, 4 rows/block.
// ---------------------------------------------------------------------------
__global__ __launch_bounds__(256) void outbn_kernel(
    const float* __restrict__ vals, const float* __restrict__ stats,
    const float* __restrict__ gamma, const float* __restrict__ beta,
    const float* __restrict__ Wc, const float* __restrict__ bc,
    float* __restrict__ out) {
  __shared__ float sW[NCLS][TRD];
  __shared__ float sb[NCLS];
  __shared__ float red[4][NCLS];
  const int tid = threadIdx.x;
  const int o = tid;                   // 0..255
  float s1 = 0.f, s2 = 0.f;
#pragma unroll
  for (int k = 0; k < NSTATBUF; ++k) {
    s1 += stats[k * 2 * TRD + o];
    s2 += stats[k * 2 * TRD + TRD + o];
  }
  const float invN = 1.0f / (float)NROWS;
  const float mu  = s1 * invN;
  const float var = s2 * invN - mu * mu;
  const float inv = 1.0f / sqrtf(var + EPSV);
  const float g = gamma[o] * inv;
  const float bterm = beta[o] - mu * g;
  float v[NCLS];
#pragma unroll
  for (int c = 0; c < NCLS; ++c) {
    const float wc = Wc[c * TRD + o];
    sW[c][o] = wc * g;
    v[c] = wc * bterm;
  }
#pragma unroll
  for (int s = 1; s < 64; s <<= 1) {
#pragma unroll
    for (int c = 0; c < NCLS; ++c) v[c] += __shfl_xor(v[c], s, 64);
  }
  if ((tid & 63) == 0) {
#pragma unroll
    for (int c = 0; c < NCLS; ++c) red[tid >> 6][c] = v[c];
  }
  __syncthreads();
  if (tid < NCLS)
    sb[tid] = bc[tid] + red[0][tid] + red[1][tid] + red[2][tid] + red[3][tid];
  __syncthreads();

  const int lane = tid & 63;
  const int row = blockIdx.x * 4 + (tid >> 6);
  float vv[TRD / 64];
#pragma unroll
  for (int t = 0; t < TRD / 64; ++t)
    vv[t] = vals[(size_t)row * TRD + lane + 64 * t];
#pragma unroll
  for (int c = 0; c < NCLS; ++c) {
    float p = 0.f;
#pragma unroll
    for (int t = 0; t < TRD / 64; ++t)
      p = fmaf(vv[t], sW[c][lane + 64 * t], p);
#pragma unroll
    for (int s = 1; s < 64; s <<= 1) p += __shfl_xor(p, s, 64);
    if (lane == 0) out[(size_t)row * NCLS + c] = p + sb[c];
  }
}

// ---------------------------------------------------------------------------
extern "C" void kernel_launch(void* const* d_in, const int* in_sizes, int n_in,
                              void* d_out, int out_size, void* d_ws, size_t ws_size,
                              hipStream_t stream) {
  (void)in_sizes; (void)n_in; (void)out_size; (void)ws_size;
  const float* nodes = (const float*)d_in[0];
  const float* edges = (const float*)d_in[1];
  const float* dist  = (const float*)d_in[2];
  const int*   mask  = (const int*)d_in[3];
  const float* Wq  = (const float*)d_in[4];
  const float* bq  = (const float*)d_in[5];
  const float* Wk  = (const float*)d_in[6];
  const float* bk  = (const float*)d_in[7];
  const float* Wnv = (const float*)d_in[8];
  const float* bnv = (const float*)d_in[9];
  const float* Wev = (const float*)d_in[10];
  const float* bev = (const float*)d_in[11];
  const float* Wt  = (const float*)d_in[12];
  const float* bt  = (const float*)d_in[13];
  const float* gamma = (const float*)d_in[14];
  const float* beta  = (const float*)d_in[15];
  const float* Wc  = (const float*)d_in[16];
  const float* bc  = (const float*)d_in[17];

  float* ws    = (float*)d_ws;
  float* Q     = ws;                               // 2048*128
  float* K     = Q   + (size_t)NROWS * QKD;        // 2048*128
  float* NV    = K   + (size_t)NROWS * QKD;        // 2048*128
  float* pnv   = NV  + (size_t)NROWS * NVD;        // 4*2048*128
  float* pm    = pnv + (size_t)NCHUNK * NROWS * NVD;  // 4*2048
  float* pl    = pm  + (size_t)NCHUNK * NROWS;     // 4*2048
  float* pse   = pl  + (size_t)NCHUNK * NROWS;     // 4*2048
  float* vals  = pse + (size_t)NCHUNK * NROWS;     // 2048*256
  float* stats = vals + (size_t)NROWS * TRD;       // 8*512 (sum|sqsum)
  float* outp  = (float*)d_out;

  qkv_kernel<<<NROWS / 2, 256, 0, stream>>>(nodes, Wq, bq, Wk, bk, Wnv, bnv,
                                            Q, K, NV, stats);
  flashA_kernel<<<NBATCH * NCHUNK * (NNODE / RB), 256, 0, stream>>>(
      Q, K, NV, edges, dist, mask, pnv, pm, pl, pse);
  passBtrans_kernel<<<NROWS / 4, 256, 0, stream>>>(pnv, pm, pl, pse, Wev, bev,
                                                   Wt, bt, vals, stats);
  outbn_kernel<<<NROWS / 4, 256, 0, stream>>>(vals, stats, gamma, beta,
                                              Wc, bc, outp);
}